// Round 1
// baseline (332.999 us; speedup 1.0000x reference)
//
#include <hip/hip_runtime.h>
#include <cstdint>

// Problem constants (B=16, H=256, W=256, C=16, HID=64)
#define NPIX (16 * 256 * 256)   // 1,048,576 pixels
#define HWPIX 65536             // 256*256
#define THRV 0.1f

// ---------------------------------------------------------------------------
// Kernel 1: per-pixel channel sum s = sum_c x[c], and a_pre = x[ch 3]
// ---------------------------------------------------------------------------
__global__ __launch_bounds__(256) void k_prep(const float* __restrict__ x,
                                              float* __restrict__ s,
                                              float* __restrict__ apre) {
    int p = blockIdx.x * 256 + threadIdx.x;
    const float4* xp = (const float4*)(x + (size_t)p * 16);
    float4 a = xp[0], b = xp[1], c = xp[2], d = xp[3];
    float sum = ((a.x + a.y) + (a.z + a.w)) + ((b.x + b.y) + (b.z + b.w)) +
                ((c.x + c.y) + (c.z + c.w)) + ((d.x + d.y) + (d.z + d.w));
    s[p] = sum;
    apre[p] = a.w;  // channel 3
}

// ---------------------------------------------------------------------------
// Kernel 2: sobel + 3-layer MLP per pixel, fp32. Writes x_new to out, a_new.
// Weights staged in LDS (wave-uniform broadcast reads = conflict-free).
// w1 is collapsed: rows 16..31 (all sx) and 32..47 (all sy) are pre-summed.
// ---------------------------------------------------------------------------
__global__ __launch_bounds__(256) void k_main(const float* __restrict__ x,
                                              const float* __restrict__ s,
                                              const float* __restrict__ w1,
                                              const float* __restrict__ b1,
                                              const float* __restrict__ w2,
                                              const float* __restrict__ b2,
                                              const float* __restrict__ w3,
                                              float* __restrict__ out,
                                              float* __restrict__ anew) {
    __shared__ float sw1[18 * 64];  // rows 0..15 = w1 rows; 16=sum(16..31); 17=sum(32..47)
    __shared__ float sb1[64];
    __shared__ float sw2[64 * 64];
    __shared__ float sb2[64];
    __shared__ float sw3[64 * 16];

    const int t = threadIdx.x;

    for (int i = t; i < 16 * 64; i += 256) sw1[i] = w1[i];
    for (int i = t; i < 128; i += 256) {  // threads 0..127: the two summed rows
        int blk = i >> 6;   // 0 -> sx rows (16..31), 1 -> sy rows (32..47)
        int o = i & 63;
        const float* base = w1 + (16 + blk * 16) * 64 + o;
        float acc = 0.f;
#pragma unroll
        for (int r = 0; r < 16; ++r) acc += base[r * 64];
        sw1[(16 + blk) * 64 + o] = acc;
    }
    if (t < 64) sb1[t] = b1[t];
    for (int i = t; i < 64 * 64; i += 256) sw2[i] = w2[i];
    if (t < 64) sb2[t] = b2[t];
    for (int i = t; i < 64 * 16; i += 256) sw3[i] = w3[i];
    __syncthreads();

    const int p = blockIdx.x * 256 + t;
    const int b = p >> 16;         // H*W = 65536
    const int rem = p & 65535;
    const int yy = rem >> 8;       // W = 256; each block is one image row
    const int xx = rem & 255;

    // --- sobel from s (zero padding; lax.conv = cross-correlation, no flip)
    const float* sbase = s + (size_t)b * HWPIX;
    float sv[3][3];
#pragma unroll
    for (int dy = -1; dy <= 1; ++dy) {
        int y2 = yy + dy;
        bool yok = (unsigned)y2 < 256u;  // wave-uniform
#pragma unroll
        for (int dx = -1; dx <= 1; ++dx) {
            int x2 = xx + dx;
            float v = 0.f;
            if (yok && (unsigned)x2 < 256u) v = sbase[y2 * 256 + x2];
            sv[dy + 1][dx + 1] = v;
        }
    }
    float gx = (-sv[0][0] + sv[0][2] - 2.f * sv[1][0] + 2.f * sv[1][2] - sv[2][0] + sv[2][2]) * 0.125f;
    float gy = (-sv[0][0] - 2.f * sv[0][1] - sv[0][2] + sv[2][0] + 2.f * sv[2][1] + sv[2][2]) * 0.125f;

    // --- load own pixel (16 channels)
    float xv[16];
    {
        const float4* xp = (const float4*)(x + (size_t)p * 16);
        float4 q0 = xp[0], q1 = xp[1], q2 = xp[2], q3 = xp[3];
        xv[0] = q0.x; xv[1] = q0.y; xv[2] = q0.z; xv[3] = q0.w;
        xv[4] = q1.x; xv[5] = q1.y; xv[6] = q1.z; xv[7] = q1.w;
        xv[8] = q2.x; xv[9] = q2.y; xv[10] = q2.z; xv[11] = q2.w;
        xv[12] = q3.x; xv[13] = q3.y; xv[14] = q3.z; xv[15] = q3.w;
    }

    // --- layer 1: h1 = relu(perc @ w1 + b1), 18 effective inputs
    float h1[64];
#pragma unroll
    for (int o = 0; o < 64; ++o)
        h1[o] = fmaf(gy, sw1[17 * 64 + o], fmaf(gx, sw1[16 * 64 + o], sb1[o]));
#pragma unroll
    for (int i = 0; i < 16; ++i) {
        float v = xv[i];
#pragma unroll
        for (int o = 0; o < 64; ++o) h1[o] = fmaf(v, sw1[i * 64 + o], h1[o]);
    }
#pragma unroll
    for (int o = 0; o < 64; ++o) h1[o] = fmaxf(h1[o], 0.f);

    // --- layers 2+3, chunked over 16 outputs of h2 at a time.
    // oc is a RUNTIME loop (nothing register-indexed by oc) to bound code size.
    float upd[16];
#pragma unroll
    for (int c = 0; c < 16; ++c) upd[c] = 0.f;
#pragma unroll 1
    for (int oc = 0; oc < 4; ++oc) {
        float h2[16];
#pragma unroll
        for (int j = 0; j < 16; ++j) h2[j] = sb2[oc * 16 + j];
#pragma unroll
        for (int i = 0; i < 64; ++i) {
            float v = h1[i];
#pragma unroll
            for (int j = 0; j < 16; ++j) h2[j] = fmaf(v, sw2[i * 64 + oc * 16 + j], h2[j]);
        }
#pragma unroll
        for (int j = 0; j < 16; ++j) {
            float v = fmaxf(h2[j], 0.f);
#pragma unroll
            for (int c = 0; c < 16; ++c) upd[c] = fmaf(v, sw3[(oc * 16 + j) * 16 + c], upd[c]);
        }
    }

    // --- x_new = x + update (ALPHA = 1)
    float xn[16];
#pragma unroll
    for (int c = 0; c < 16; ++c) xn[c] = xv[c] + upd[c];

    float4* op = (float4*)(out + (size_t)p * 16);
    op[0] = make_float4(xn[0], xn[1], xn[2], xn[3]);
    op[1] = make_float4(xn[4], xn[5], xn[6], xn[7]);
    op[2] = make_float4(xn[8], xn[9], xn[10], xn[11]);
    op[3] = make_float4(xn[12], xn[13], xn[14], xn[15]);

    anew[p] = xn[3];
}

// ---------------------------------------------------------------------------
// Kernel 3: life mask. pooled(a) > THR strictly; -inf padding == skip OOB.
// Only dead pixels get written (zeroed in place) — own-pixel only, race-free.
// ---------------------------------------------------------------------------
__global__ __launch_bounds__(256) void k_post(const float* __restrict__ apre,
                                              const float* __restrict__ anew,
                                              float* __restrict__ out) {
    int p = blockIdx.x * 256 + threadIdx.x;
    int b = p >> 16;
    int rem = p & 65535;
    int yy = rem >> 8;
    int xx = rem & 255;
    const float* ap = apre + (size_t)b * HWPIX;
    const float* an = anew + (size_t)b * HWPIX;
    float mpre = -1e30f, mpost = -1e30f;
#pragma unroll
    for (int dy = -1; dy <= 1; ++dy) {
        int y2 = yy + dy;
        if ((unsigned)y2 >= 256u) continue;
#pragma unroll
        for (int dx = -1; dx <= 1; ++dx) {
            int x2 = xx + dx;
            if ((unsigned)x2 >= 256u) continue;
            int q = y2 * 256 + x2;
            mpre = fmaxf(mpre, ap[q]);
            mpost = fmaxf(mpost, an[q]);
        }
    }
    bool alive = (mpre > THRV) && (mpost > THRV);
    if (!alive) {
        float4* op = (float4*)(out + (size_t)p * 16);
        float4 z = make_float4(0.f, 0.f, 0.f, 0.f);
        op[0] = z; op[1] = z; op[2] = z; op[3] = z;
    }
}

// ---------------------------------------------------------------------------
extern "C" void kernel_launch(void* const* d_in, const int* in_sizes, int n_in,
                              void* d_out, int out_size, void* d_ws, size_t ws_size,
                              hipStream_t stream) {
    const float* x  = (const float*)d_in[0];
    const float* w1 = (const float*)d_in[1];
    const float* b1 = (const float*)d_in[2];
    const float* w2 = (const float*)d_in[3];
    const float* b2 = (const float*)d_in[4];
    const float* w3 = (const float*)d_in[5];
    float* out = (float*)d_out;

    float* s    = (float*)d_ws;        // NPIX floats
    float* apre = s + NPIX;            // NPIX floats
    float* anew = apre + NPIX;         // NPIX floats  (12 MB total)

    dim3 grid(NPIX / 256), block(256);
    hipLaunchKernelGGL(k_prep, grid, block, 0, stream, x, s, apre);
    hipLaunchKernelGGL(k_main, grid, block, 0, stream, x, s, w1, b1, w2, b2, w3, out, anew);
    hipLaunchKernelGGL(k_post, grid, block, 0, stream, apre, anew, out);
}

// Round 2
// 149.335 us; speedup vs baseline: 2.2299x; 2.2299x over previous
//
#include <hip/hip_runtime.h>
#include <hip/hip_bf16.h>
#include <cstdint>

// Problem constants (B=16, H=256, W=256, C=16, HID=64)
#define NPIX (16 * 256 * 256)
#define HWPIX 65536
#define THRV 0.1f
#define TPW 8   // tiles (of 16 pixels) per wave

typedef __bf16 bf16x8 __attribute__((ext_vector_type(8)));
typedef float  f32x4  __attribute__((ext_vector_type(4)));

static __device__ inline bf16x8 pack8(float4 a, float4 b) {
    bf16x8 v;
    v[0] = (__bf16)a.x; v[1] = (__bf16)a.y; v[2] = (__bf16)a.z; v[3] = (__bf16)a.w;
    v[4] = (__bf16)b.x; v[5] = (__bf16)b.y; v[6] = (__bf16)b.z; v[7] = (__bf16)b.w;
    return v;
}

// ---------------------------------------------------------------------------
// Kernel 1: s = sum_c x[c], apre = x[ch 3]
// ---------------------------------------------------------------------------
__global__ __launch_bounds__(256) void k_prep(const float* __restrict__ x,
                                              float* __restrict__ s,
                                              float* __restrict__ apre) {
    int p = blockIdx.x * 256 + threadIdx.x;
    const float4* xp = (const float4*)(x + (size_t)p * 16);
    float4 a = xp[0], b = xp[1], c = xp[2], d = xp[3];
    float sum = ((a.x + a.y) + (a.z + a.w)) + ((b.x + b.y) + (b.z + b.w)) +
                ((c.x + c.y) + (c.z + c.w)) + ((d.x + d.y) + (d.z + d.w));
    s[p] = sum;
    apre[p] = a.w;
}

// ---------------------------------------------------------------------------
// Kernel 2: MFMA MLP. Each wave owns a 16-pixel tile; weights live in VGPRs
// as B-fragments (loaded once), activations bounce via per-wave swizzled LDS.
// mfma_f32_16x16x32_bf16:  A: row=lane&15, k=(lane>>4)*8+j
//                          B: col=lane&15, k=(lane>>4)*8+j
//                          C: col=lane&15, row=(lane>>4)*4+reg
// ---------------------------------------------------------------------------
__global__ __launch_bounds__(256) void k_mfma(const float* __restrict__ x,
                                              const float* __restrict__ s,
                                              const float* __restrict__ w1,
                                              const float* __restrict__ b1,
                                              const float* __restrict__ w2,
                                              const float* __restrict__ b2,
                                              const float* __restrict__ w3,
                                              float* __restrict__ out,
                                              float* __restrict__ anew) {
    __shared__ float hbuf[4][16 * 64];   // per-wave h bounce, kg-XOR swizzled
    __shared__ float xld[4][16 * 20];    // per-wave x tile (stride 20 = 16B aligned)

    const int tid  = threadIdx.x;
    const int wv   = tid >> 6;
    const int lane = tid & 63;
    const int r    = lane & 15;   // A-row / B-col / C-col index
    const int g    = lane >> 4;   // k-group

    // ---- weight fragments (one-time, L2-resident scattered loads) ----
    // Layer 1: effective K=18 (x[0..15], gx, gy), padded to 32.
    bf16x8 w1f[4];
#pragma unroll
    for (int n = 0; n < 4; ++n) {
        const int c = n * 16 + r;
#pragma unroll
        for (int j = 0; j < 8; ++j) {
            const int k = g * 8 + j;
            float v = 0.f;
            if (k < 16) v = w1[k * 64 + c];
            else if (k == 16) {
                for (int t = 0; t < 16; ++t) v += w1[(16 + t) * 64 + c];  // sx rows
            } else if (k == 17) {
                for (int t = 0; t < 16; ++t) v += w1[(32 + t) * 64 + c];  // sy rows
            }
            w1f[n][j] = (__bf16)v;
        }
    }
    bf16x8 w2f[2][4];
#pragma unroll
    for (int s2 = 0; s2 < 2; ++s2)
#pragma unroll
        for (int n = 0; n < 4; ++n)
#pragma unroll
            for (int j = 0; j < 8; ++j)
                w2f[s2][n][j] = (__bf16)w2[(s2 * 32 + g * 8 + j) * 64 + n * 16 + r];
    bf16x8 w3f[2];
#pragma unroll
    for (int s2 = 0; s2 < 2; ++s2)
#pragma unroll
        for (int j = 0; j < 8; ++j)
            w3f[s2][j] = (__bf16)w3[(s2 * 32 + g * 8 + j) * 16 + r];
    float b1v[4], b2v[4];
#pragma unroll
    for (int n = 0; n < 4; ++n) { b1v[n] = b1[n * 16 + r]; b2v[n] = b2[n * 16 + r]; }

    float* hb = hbuf[wv];
    float* xl = xld[wv];
    const int base = blockIdx.x * (64 * TPW) + wv * (16 * TPW);

#pragma unroll 1
    for (int t = 0; t < TPW; ++t) {
        const int pb = base + t * 16;

        // ---- A1 fragment (perc) + x tile staging ----
        bf16x8 a1;
        if (g < 2) {
            const float* xp = x + (size_t)(pb + r) * 16 + g * 8;
            float4 f0 = ((const float4*)xp)[0];
            float4 f1 = ((const float4*)xp)[1];
            a1 = pack8(f0, f1);
            float* xw = xl + r * 20 + g * 8;
            ((float4*)xw)[0] = f0;
            ((float4*)xw)[1] = f1;
        } else if (g == 2) {
            const int pp = pb + r;
            const float* sb = s + ((size_t)(pp >> 16) << 16);
            const int rem = pp & 65535;
            const int yy = rem >> 8, xx = rem & 255;
            float sv[3][3];
#pragma unroll
            for (int dy = -1; dy <= 1; ++dy) {
                const int y2 = yy + dy;
                const bool yok = (unsigned)y2 < 256u;
#pragma unroll
                for (int dx = -1; dx <= 1; ++dx) {
                    const int x2 = xx + dx;
                    sv[dy + 1][dx + 1] = (yok && (unsigned)x2 < 256u) ? sb[y2 * 256 + x2] : 0.f;
                }
            }
            float gx = (-sv[0][0] + sv[0][2] - 2.f * sv[1][0] + 2.f * sv[1][2] - sv[2][0] + sv[2][2]) * 0.125f;
            float gy = (-sv[0][0] - 2.f * sv[0][1] - sv[0][2] + sv[2][0] + 2.f * sv[2][1] + sv[2][2]) * 0.125f;
            a1 = pack8(make_float4(gx, gy, 0.f, 0.f), make_float4(0.f, 0.f, 0.f, 0.f));
        } else {
            a1 = pack8(make_float4(0.f, 0.f, 0.f, 0.f), make_float4(0.f, 0.f, 0.f, 0.f));
        }

        // ---- Layer 1 ----
        f32x4 acc1[4];
#pragma unroll
        for (int n = 0; n < 4; ++n) {
            acc1[n] = (f32x4){b1v[n], b1v[n], b1v[n], b1v[n]};
            acc1[n] = __builtin_amdgcn_mfma_f32_16x16x32_bf16(a1, w1f[n], acc1[n], 0, 0, 0);
        }
        // write h1 (relu) into swizzled LDS:  dw = p*64 + ((kg^ (p&7))<<3) + (k&7)
#pragma unroll
        for (int n = 0; n < 4; ++n)
#pragma unroll
            for (int q = 0; q < 4; ++q) {
                const int p = g * 4 + q;
                const int c = n * 16 + r;
                hb[p * 64 + (((c >> 3) ^ (p & 7)) << 3) + (c & 7)] = fmaxf(acc1[n][q], 0.f);
            }

        // ---- read A2 ----
        bf16x8 a2[2];
#pragma unroll
        for (int s2 = 0; s2 < 2; ++s2) {
            const int off = r * 64 + (((s2 * 4 + g) ^ (r & 7)) << 3);
            float4 u0 = ((float4*)(hb + off))[0];
            float4 u1 = ((float4*)(hb + off))[1];
            a2[s2] = pack8(u0, u1);
        }

        // ---- Layer 2 ----
        f32x4 acc2[4];
#pragma unroll
        for (int n = 0; n < 4; ++n) {
            acc2[n] = (f32x4){b2v[n], b2v[n], b2v[n], b2v[n]};
#pragma unroll
            for (int s2 = 0; s2 < 2; ++s2)
                acc2[n] = __builtin_amdgcn_mfma_f32_16x16x32_bf16(a2[s2], w2f[s2][n], acc2[n], 0, 0, 0);
        }
        // write h2 (relu), same swizzle (overwrites h1 — same-wave ordering via lgkmcnt)
#pragma unroll
        for (int n = 0; n < 4; ++n)
#pragma unroll
            for (int q = 0; q < 4; ++q) {
                const int p = g * 4 + q;
                const int c = n * 16 + r;
                hb[p * 64 + (((c >> 3) ^ (p & 7)) << 3) + (c & 7)] = fmaxf(acc2[n][q], 0.f);
            }

        // ---- read A3 ----
        bf16x8 a3[2];
#pragma unroll
        for (int s2 = 0; s2 < 2; ++s2) {
            const int off = r * 64 + (((s2 * 4 + g) ^ (r & 7)) << 3);
            float4 u0 = ((float4*)(hb + off))[0];
            float4 u1 = ((float4*)(hb + off))[1];
            a3[s2] = pack8(u0, u1);
        }

        // ---- Layer 3 ----
        f32x4 acc3 = (f32x4){0.f, 0.f, 0.f, 0.f};
#pragma unroll
        for (int s2 = 0; s2 < 2; ++s2)
            acc3 = __builtin_amdgcn_mfma_f32_16x16x32_bf16(a3[s2], w3f[s2], acc3, 0, 0, 0);

        // ---- residual + store (fp32 x from LDS) ----
#pragma unroll
        for (int q = 0; q < 4; ++q) {
            const int p = g * 4 + q;
            const float v = xl[p * 20 + r] + acc3[q];
            out[(size_t)(pb + p) * 16 + r] = v;
            if (r == 3) anew[pb + p] = v;
        }
    }
}

// ---------------------------------------------------------------------------
// Kernel 3: life mask; zero dead pixels in place.
// ---------------------------------------------------------------------------
__global__ __launch_bounds__(256) void k_post(const float* __restrict__ apre,
                                              const float* __restrict__ anew,
                                              float* __restrict__ out) {
    int p = blockIdx.x * 256 + threadIdx.x;
    int b = p >> 16;
    int rem = p & 65535;
    int yy = rem >> 8;
    int xx = rem & 255;
    const float* ap = apre + (size_t)b * HWPIX;
    const float* an = anew + (size_t)b * HWPIX;
    float mpre = -1e30f, mpost = -1e30f;
#pragma unroll
    for (int dy = -1; dy <= 1; ++dy) {
        int y2 = yy + dy;
        if ((unsigned)y2 >= 256u) continue;
#pragma unroll
        for (int dx = -1; dx <= 1; ++dx) {
            int x2 = xx + dx;
            if ((unsigned)x2 >= 256u) continue;
            int q = y2 * 256 + x2;
            mpre = fmaxf(mpre, ap[q]);
            mpost = fmaxf(mpost, an[q]);
        }
    }
    bool alive = (mpre > THRV) && (mpost > THRV);
    if (!alive) {
        float4* op = (float4*)(out + (size_t)p * 16);
        float4 z = make_float4(0.f, 0.f, 0.f, 0.f);
        op[0] = z; op[1] = z; op[2] = z; op[3] = z;
    }
}

// ---------------------------------------------------------------------------
extern "C" void kernel_launch(void* const* d_in, const int* in_sizes, int n_in,
                              void* d_out, int out_size, void* d_ws, size_t ws_size,
                              hipStream_t stream) {
    const float* x  = (const float*)d_in[0];
    const float* w1 = (const float*)d_in[1];
    const float* b1 = (const float*)d_in[2];
    const float* w2 = (const float*)d_in[3];
    const float* b2 = (const float*)d_in[4];
    const float* w3 = (const float*)d_in[5];
    float* out = (float*)d_out;

    float* s    = (float*)d_ws;   // NPIX floats
    float* apre = s + NPIX;       // NPIX floats
    float* anew = apre + NPIX;    // NPIX floats (12 MB total)

    hipLaunchKernelGGL(k_prep, dim3(NPIX / 256), dim3(256), 0, stream, x, s, apre);
    hipLaunchKernelGGL(k_mfma, dim3(NPIX / (64 * TPW)), dim3(256), 0, stream,
                       x, s, w1, b1, w2, b2, w3, out, anew);
    hipLaunchKernelGGL(k_post, dim3(NPIX / 256), dim3(256), 0, stream, apre, anew, out);
}

// Round 3
// 62.699 us; speedup vs baseline: 5.3111x; 2.3818x over previous
//
#include <hip/hip_runtime.h>
#include <hip/hip_bf16.h>
#include <cstdint>

#define NPIX (16 * 256 * 256)
#define HWPIX 65536
#define THRV 0.1f
#define TPW 8   // 16-pixel tiles per wave

typedef __bf16 bf16x8 __attribute__((ext_vector_type(8)));
typedef float  f32x4  __attribute__((ext_vector_type(4)));

// wpack: per-lane weight fragments, slot-major (slot*64 + lane), float4 each.
//  0..3   w1f[n]        (bf16x8)   A-frag of W1^T (+sobel-sum rows, +b1 slot)
//  4..11  w2f[s*4+n]    (bf16x8)   A-frag of W2^T under psi
//  12..13 w3f[s]        (bf16x8)   A-frag of W3^T under psi
//  14..17 b2v[n]        (f32x4)    bias2 in C-layout
#define NSLOT 18

// ---------------------------------------------------------------------------
// k_pack: one wave builds the per-lane fragment image (runs once per call).
// psi(s,g,j) = (2s + (j>>2))*16 + g*4 + (j&3)  — chosen so layer N's C regs
// ARE layer N+1's B-frag: b[s][j] = j<4 ? acc[2s][j] : acc[2s+1][j-4].
// ---------------------------------------------------------------------------
__global__ __launch_bounds__(64) void k_pack(const float* __restrict__ w1,
                                             const float* __restrict__ b1,
                                             const float* __restrict__ w2,
                                             const float* __restrict__ b2,
                                             const float* __restrict__ w3,
                                             float4* __restrict__ wpack) {
    const int lane = threadIdx.x;
    const int r = lane & 15, g = lane >> 4;

    // layer 1: k-slots (g,j): j<4 -> x channel g*4+j; (0,4)=gx (sx-summed rows);
    // (0,5)=gy (sy-summed); (1,4)=bias (activation 1.0); rest 0.
#pragma unroll
    for (int n = 0; n < 4; ++n) {
        const int c = n * 16 + r;
        bf16x8 f;
#pragma unroll
        for (int j = 0; j < 8; ++j) {
            float v = 0.f;
            if (j < 4) v = w1[(g * 4 + j) * 64 + c];
            else if (g == 0 && j == 4) { for (int t = 0; t < 16; ++t) v += w1[(16 + t) * 64 + c]; }
            else if (g == 0 && j == 5) { for (int t = 0; t < 16; ++t) v += w1[(32 + t) * 64 + c]; }
            else if (g == 1 && j == 4) v = b1[c];
            f[j] = (__bf16)v;
        }
        wpack[n * 64 + lane] = *(const float4*)&f;
    }
#pragma unroll
    for (int s = 0; s < 2; ++s)
#pragma unroll
        for (int n = 0; n < 4; ++n) {
            bf16x8 f;
#pragma unroll
            for (int j = 0; j < 8; ++j) {
                const int psi = (2 * s + (j >> 2)) * 16 + g * 4 + (j & 3);
                f[j] = (__bf16)w2[psi * 64 + n * 16 + r];
            }
            wpack[(4 + s * 4 + n) * 64 + lane] = *(const float4*)&f;
        }
#pragma unroll
    for (int s = 0; s < 2; ++s) {
        bf16x8 f;
#pragma unroll
        for (int j = 0; j < 8; ++j) {
            const int psi = (2 * s + (j >> 2)) * 16 + g * 4 + (j & 3);
            f[j] = (__bf16)w3[psi * 16 + r];
        }
        wpack[(12 + s) * 64 + lane] = *(const float4*)&f;
    }
#pragma unroll
    for (int n = 0; n < 4; ++n) {
        f32x4 v;
#pragma unroll
        for (int q = 0; q < 4; ++q) v[q] = b2[n * 16 + g * 4 + q];
        wpack[(14 + n) * 64 + lane] = *(const float4*)&v;
    }
}

// ---------------------------------------------------------------------------
// k_prep: s = sum_c x[c], apre = x[ch3]
// ---------------------------------------------------------------------------
__global__ __launch_bounds__(256) void k_prep(const float* __restrict__ x,
                                              float* __restrict__ s,
                                              float* __restrict__ apre) {
    int p = blockIdx.x * 256 + threadIdx.x;
    const float4* xp = (const float4*)(x + (size_t)p * 16);
    float4 a = xp[0], b = xp[1], c = xp[2], d = xp[3];
    float sum = ((a.x + a.y) + (a.z + a.w)) + ((b.x + b.y) + (b.z + b.w)) +
                ((c.x + c.y) + (c.z + c.w)) + ((d.x + d.y) + (d.z + d.w));
    s[p] = sum;
    apre[p] = a.w;
}

// ---------------------------------------------------------------------------
// k_mfma: fully in-register 3-layer MLP. D = mfma(W^T, act): pixel on lane&15,
// channels on (g,reg). No LDS at all. Lane (g,r): owns pixel r's channels
// g*4..g*4+3 (clean float4 load/store), sobel distributed 3 loads/lane.
// ---------------------------------------------------------------------------
__global__ __launch_bounds__(256) void k_mfma(const float* __restrict__ x,
                                              const float* __restrict__ s,
                                              const float4* __restrict__ wpack,
                                              float* __restrict__ out,
                                              float* __restrict__ anew) {
    const int tid = threadIdx.x;
    const int wv = tid >> 6, lane = tid & 63;
    const int r = lane & 15, g = lane >> 4;

    // ---- per-wave fragment state (coalesced 1KB/slot loads) ----
    bf16x8 w1f[4], w2f[2][4], w3f[2];
    f32x4 b2v[4];
#pragma unroll
    for (int n = 0; n < 4; ++n) { float4 t = wpack[n * 64 + lane]; w1f[n] = *(bf16x8*)&t; }
#pragma unroll
    for (int s2 = 0; s2 < 2; ++s2)
#pragma unroll
        for (int n = 0; n < 4; ++n) { float4 t = wpack[(4 + s2 * 4 + n) * 64 + lane]; w2f[s2][n] = *(bf16x8*)&t; }
#pragma unroll
    for (int s2 = 0; s2 < 2; ++s2) { float4 t = wpack[(12 + s2) * 64 + lane]; w3f[s2] = *(bf16x8*)&t; }
#pragma unroll
    for (int n = 0; n < 4; ++n) { float4 t = wpack[(14 + n) * 64 + lane]; b2v[n] = *(f32x4*)&t; }

    const int base = blockIdx.x * (64 * TPW) + wv * (16 * TPW);

    // issue loads for tile t: own x float4 + 3 sobel s-values (row y+g-1)
    auto issue = [&](int t, float4& xf_, float& c0_, float& c1_, float& c2_) {
        const int pb = base + t * 16;                 // 16 pixels, same image row
        xf_ = *(const float4*)(x + (size_t)(pb + r) * 16 + g * 4);
        const int b = pb >> 16;
        const int y = (pb >> 8) & 255;
        const int xb = pb & 255;
        const int y2 = y + g - 1;
        const int xc = xb + r;
        const bool rowok = (g < 3) & ((unsigned)y2 < 256u);
        const float* sb = s + ((size_t)b << 16);
        c0_ = (rowok && xc > 0)   ? sb[y2 * 256 + xc - 1] : 0.f;
        c1_ = rowok               ? sb[y2 * 256 + xc]     : 0.f;
        c2_ = (rowok && xc < 255) ? sb[y2 * 256 + xc + 1] : 0.f;
    };
    // per-row sobel partials -> cross-g sum (all lanes end up with gx,gy)
    auto combine = [&](float c0_, float c1_, float c2_, float& gx_, float& gy_) {
        float px = (c2_ - c0_) * (g == 1 ? 0.25f : 0.125f);
        float py = (float)(g - 1) * (c0_ + 2.f * c1_ + c2_) * 0.125f;
        gx_ = __shfl(px, r) + __shfl(px, r + 16) + __shfl(px, r + 32);
        gy_ = __shfl(py, r) + __shfl(py, r + 16) + __shfl(py, r + 32);
    };

    float4 xf; float c0, c1, c2, gx, gy;
    issue(0, xf, c0, c1, c2);
    combine(c0, c1, c2, gx, gy);
    float4 xfn; float c0n = 0.f, c1n = 0.f, c2n = 0.f;

#pragma unroll 1
    for (int t = 0; t < TPW; ++t) {
        const int pb = base + t * 16;
        if (t + 1 < TPW) issue(t + 1, xfn, c0n, c1n, c2n);

        // B1 fragment
        bf16x8 a1;
        a1[0] = (__bf16)xf.x; a1[1] = (__bf16)xf.y;
        a1[2] = (__bf16)xf.z; a1[3] = (__bf16)xf.w;
        a1[4] = (__bf16)(g == 0 ? gx : (g == 1 ? 1.f : 0.f));
        a1[5] = (__bf16)(g == 0 ? gy : 0.f);
        a1[6] = (__bf16)0.f; a1[7] = (__bf16)0.f;

        // layer 1 (bias via k-slot)
        f32x4 acc1[4];
#pragma unroll
        for (int n = 0; n < 4; ++n)
            acc1[n] = __builtin_amdgcn_mfma_f32_16x16x32_bf16(
                w1f[n], a1, (f32x4){0.f, 0.f, 0.f, 0.f}, 0, 0, 0);

        // relu + repack: C regs ARE the next B-frag under psi
        bf16x8 bf2[2];
#pragma unroll
        for (int s2 = 0; s2 < 2; ++s2)
#pragma unroll
            for (int j = 0; j < 4; ++j) {
                bf2[s2][j]     = (__bf16)fmaxf(acc1[2 * s2][j], 0.f);
                bf2[s2][4 + j] = (__bf16)fmaxf(acc1[2 * s2 + 1][j], 0.f);
            }

        // layer 2
        f32x4 acc2[4];
#pragma unroll
        for (int n = 0; n < 4; ++n) {
            acc2[n] = b2v[n];
            acc2[n] = __builtin_amdgcn_mfma_f32_16x16x32_bf16(w2f[0][n], bf2[0], acc2[n], 0, 0, 0);
            acc2[n] = __builtin_amdgcn_mfma_f32_16x16x32_bf16(w2f[1][n], bf2[1], acc2[n], 0, 0, 0);
        }

        bf16x8 bf3[2];
#pragma unroll
        for (int s2 = 0; s2 < 2; ++s2)
#pragma unroll
            for (int j = 0; j < 4; ++j) {
                bf3[s2][j]     = (__bf16)fmaxf(acc2[2 * s2][j], 0.f);
                bf3[s2][4 + j] = (__bf16)fmaxf(acc2[2 * s2 + 1][j], 0.f);
            }

        // layer 3
        f32x4 acc3 = __builtin_amdgcn_mfma_f32_16x16x32_bf16(
            w3f[0], bf3[0], (f32x4){0.f, 0.f, 0.f, 0.f}, 0, 0, 0);
        acc3 = __builtin_amdgcn_mfma_f32_16x16x32_bf16(w3f[1], bf3[1], acc3, 0, 0, 0);

        // residual + store: lane owns pixel r, channels g*4..g*4+3
        float4 xn = make_float4(xf.x + acc3[0], xf.y + acc3[1],
                                xf.z + acc3[2], xf.w + acc3[3]);
        *(float4*)(out + (size_t)(pb + r) * 16 + g * 4) = xn;
        if (g == 0) anew[pb + r] = xn.w;  // channel 3

        if (t + 1 < TPW) { combine(c0n, c1n, c2n, gx, gy); xf = xfn; }
    }
}

// ---------------------------------------------------------------------------
// k_post: life mask; zero dead pixels in place.
// ---------------------------------------------------------------------------
__global__ __launch_bounds__(256) void k_post(const float* __restrict__ apre,
                                              const float* __restrict__ anew,
                                              float* __restrict__ out) {
    int p = blockIdx.x * 256 + threadIdx.x;
    int b = p >> 16;
    int rem = p & 65535;
    int yy = rem >> 8;
    int xx = rem & 255;
    const float* ap = apre + (size_t)b * HWPIX;
    const float* an = anew + (size_t)b * HWPIX;
    float mpre = -1e30f, mpost = -1e30f;
#pragma unroll
    for (int dy = -1; dy <= 1; ++dy) {
        int y2 = yy + dy;
        if ((unsigned)y2 >= 256u) continue;
#pragma unroll
        for (int dx = -1; dx <= 1; ++dx) {
            int x2 = xx + dx;
            if ((unsigned)x2 >= 256u) continue;
            int q = y2 * 256 + x2;
            mpre = fmaxf(mpre, ap[q]);
            mpost = fmaxf(mpost, an[q]);
        }
    }
    bool alive = (mpre > THRV) && (mpost > THRV);
    if (!alive) {
        float4* op = (float4*)(out + (size_t)p * 16);
        float4 z = make_float4(0.f, 0.f, 0.f, 0.f);
        op[0] = z; op[1] = z; op[2] = z; op[3] = z;
    }
}

// ---------------------------------------------------------------------------
extern "C" void kernel_launch(void* const* d_in, const int* in_sizes, int n_in,
                              void* d_out, int out_size, void* d_ws, size_t ws_size,
                              hipStream_t stream) {
    const float* x  = (const float*)d_in[0];
    const float* w1 = (const float*)d_in[1];
    const float* b1 = (const float*)d_in[2];
    const float* w2 = (const float*)d_in[3];
    const float* b2 = (const float*)d_in[4];
    const float* w3 = (const float*)d_in[5];
    float* out = (float*)d_out;

    float*  s     = (float*)d_ws;          // NPIX floats
    float*  apre  = s + NPIX;              // NPIX floats
    float*  anew  = apre + NPIX;           // NPIX floats
    float4* wpack = (float4*)(anew + NPIX); // NSLOT*64 float4 (18 KB)

    hipLaunchKernelGGL(k_pack, dim3(1), dim3(64), 0, stream, w1, b1, w2, b2, w3, wpack);
    hipLaunchKernelGGL(k_prep, dim3(NPIX / 256), dim3(256), 0, stream, x, s, apre);
    hipLaunchKernelGGL(k_mfma, dim3(NPIX / (64 * TPW)), dim3(256), 0, stream,
                       x, s, wpack, out, anew);
    hipLaunchKernelGGL(k_post, dim3(NPIX / 256), dim3(256), 0, stream, apre, anew, out);
}

// Round 4
// 51.201 us; speedup vs baseline: 6.5037x; 1.2245x over previous
//
#include <hip/hip_runtime.h>
#include <hip/hip_bf16.h>
#include <cstdint>

#define NPIX (16 * 256 * 256)
#define HWPIX 65536
#define THRV 0.1f
#define TPW 8   // 16-pixel tiles per wave

typedef __bf16 bf16x8 __attribute__((ext_vector_type(8)));
typedef float  f32x4  __attribute__((ext_vector_type(4)));

// wpack slots (slot*64 + lane, float4 each):
//  0..3   w1f[n]   4..11 w2f[s*4+n]   12..13 w3f[s]   14..17 b2v[n]
#define NSLOT 18

// ---------------------------------------------------------------------------
// k_prep: block = one image row (256 px). Per pixel: s = sum_c x, then via LDS
//   hx = s(x+1)-s(x-1), hs = s(x-1)+2s(x)+s(x+1)   (separable sobel halves)
//   rpref = (rowmax3 of ch3) > THR  (pre-life, horizontal part, as 0/1 byte)
// Block 0 lanes<64 additionally build the weight fragment image (k_pack).
// psi(s,g,j) = (2s+(j>>2))*16 + g*4 + (j&3): layer N's C regs ARE layer N+1's
// B-frag, so the MLP never touches LDS.
// ---------------------------------------------------------------------------
__global__ __launch_bounds__(256) void k_prep(const float* __restrict__ x,
                                              const float* __restrict__ w1,
                                              const float* __restrict__ b1,
                                              const float* __restrict__ w2,
                                              const float* __restrict__ b2,
                                              const float* __restrict__ w3,
                                              float* __restrict__ hx,
                                              float* __restrict__ hs,
                                              unsigned char* __restrict__ rpref,
                                              float4* __restrict__ wpack) {
    __shared__ float sS[258];
    __shared__ float sA[258];
    const int tid = threadIdx.x;
    const int p = blockIdx.x * 256 + tid;

    const float4* xp = (const float4*)(x + (size_t)p * 16);
    float4 a = xp[0], b = xp[1], c = xp[2], d = xp[3];
    float sum = ((a.x + a.y) + (a.z + a.w)) + ((b.x + b.y) + (b.z + b.w)) +
                ((c.x + c.y) + (c.z + c.w)) + ((d.x + d.y) + (d.z + d.w));
    sS[tid + 1] = sum;
    sA[tid + 1] = a.w;  // channel 3
    if (tid == 0) { sS[0] = 0.f; sS[257] = 0.f; sA[0] = -1e30f; sA[257] = -1e30f; }
    __syncthreads();

    hx[p] = sS[tid + 2] - sS[tid];
    hs[p] = sS[tid] + 2.f * sS[tid + 1] + sS[tid + 2];
    float rm = fmaxf(sA[tid], fmaxf(sA[tid + 1], sA[tid + 2]));
    rpref[p] = (rm > THRV) ? 1 : 0;

    // ---- one-time weight pack (block 0, one wave) ----
    if (blockIdx.x == 0 && tid < 64) {
        const int lane = tid;
        const int r = lane & 15, g = lane >> 4;
#pragma unroll
        for (int n = 0; n < 4; ++n) {
            const int cc = n * 16 + r;
            bf16x8 f;
#pragma unroll
            for (int j = 0; j < 8; ++j) {
                float v = 0.f;
                if (j < 4) v = w1[(g * 4 + j) * 64 + cc];
                else if (g == 0 && j == 4) { for (int t = 0; t < 16; ++t) v += w1[(16 + t) * 64 + cc]; }
                else if (g == 0 && j == 5) { for (int t = 0; t < 16; ++t) v += w1[(32 + t) * 64 + cc]; }
                else if (g == 1 && j == 4) v = b1[cc];
                f[j] = (__bf16)v;
            }
            wpack[n * 64 + lane] = *(const float4*)&f;
        }
#pragma unroll
        for (int s = 0; s < 2; ++s)
#pragma unroll
            for (int n = 0; n < 4; ++n) {
                bf16x8 f;
#pragma unroll
                for (int j = 0; j < 8; ++j) {
                    const int psi = (2 * s + (j >> 2)) * 16 + g * 4 + (j & 3);
                    f[j] = (__bf16)w2[psi * 64 + n * 16 + r];
                }
                wpack[(4 + s * 4 + n) * 64 + lane] = *(const float4*)&f;
            }
#pragma unroll
        for (int s = 0; s < 2; ++s) {
            bf16x8 f;
#pragma unroll
            for (int j = 0; j < 8; ++j) {
                const int psi = (2 * s + (j >> 2)) * 16 + g * 4 + (j & 3);
                f[j] = (__bf16)w3[psi * 16 + r];
            }
            wpack[(12 + s) * 64 + lane] = *(const float4*)&f;
        }
#pragma unroll
        for (int n = 0; n < 4; ++n) {
            f32x4 v;
#pragma unroll
            for (int q = 0; q < 4; ++q) v[q] = b2[n * 16 + g * 4 + q];
            wpack[(14 + n) * 64 + lane] = *(const float4*)&v;
        }
    }
}

// ---------------------------------------------------------------------------
// k_mfma: in-register 3-layer MLP, D = mfma(W^T, act): pixel on lane&15,
// channels on (g,reg). No LDS. Wave owns 128 consecutive px of one row.
// g==0 lanes fetch 5 sobel-half values; gx=(hxm+2hx0+hxp)/8, gy=(hsp-hsm)/8.
// ---------------------------------------------------------------------------
__global__ __launch_bounds__(256) void k_mfma(const float* __restrict__ x,
                                              const float* __restrict__ hx,
                                              const float* __restrict__ hs,
                                              const float4* __restrict__ wpack,
                                              float* __restrict__ out,
                                              unsigned char* __restrict__ anewf) {
    const int tid = threadIdx.x;
    const int wv = tid >> 6, lane = tid & 63;
    const int r = lane & 15, g = lane >> 4;

    bf16x8 w1f[4], w2f[2][4], w3f[2];
    f32x4 b2v[4];
#pragma unroll
    for (int n = 0; n < 4; ++n) { float4 t = wpack[n * 64 + lane]; w1f[n] = *(bf16x8*)&t; }
#pragma unroll
    for (int s2 = 0; s2 < 2; ++s2)
#pragma unroll
        for (int n = 0; n < 4; ++n) { float4 t = wpack[(4 + s2 * 4 + n) * 64 + lane]; w2f[s2][n] = *(bf16x8*)&t; }
#pragma unroll
    for (int s2 = 0; s2 < 2; ++s2) { float4 t = wpack[(12 + s2) * 64 + lane]; w3f[s2] = *(bf16x8*)&t; }
#pragma unroll
    for (int n = 0; n < 4; ++n) { float4 t = wpack[(14 + n) * 64 + lane]; b2v[n] = *(f32x4*)&t; }

    const int base = blockIdx.x * 512 + wv * 128;   // 128 px, single row
    const int bi = base >> 16;
    const int y = (base >> 8) & 255;
    const int xb0 = base & 255;
    const bool ym = (y > 0), yp = (y < 255);
    const float* rC_hx = hx + ((size_t)bi << 16) + y * 256;
    const float* rC_hs = hs + ((size_t)bi << 16) + y * 256;

    auto issue = [&](int t, float4& xf_, float& hxm_, float& hx0_, float& hxp_,
                     float& hsm_, float& hsp_) {
        const int pb = base + t * 16;
        xf_ = *(const float4*)(x + (size_t)(pb + r) * 16 + g * 4);
        if (g == 0) {
            const int xc = xb0 + t * 16 + r;
            hxm_ = ym ? rC_hx[xc - 256] : 0.f;
            hx0_ = rC_hx[xc];
            hxp_ = yp ? rC_hx[xc + 256] : 0.f;
            hsm_ = ym ? rC_hs[xc - 256] : 0.f;
            hsp_ = yp ? rC_hs[xc + 256] : 0.f;
        }
    };

    float4 xf; float hxm = 0, hx0 = 0, hxp = 0, hsm = 0, hsp = 0;
    issue(0, xf, hxm, hx0, hxp, hsm, hsp);
    float4 xfn; float hxmn = 0, hx0n = 0, hxpn = 0, hsmn = 0, hspn = 0;

#pragma unroll 1
    for (int t = 0; t < TPW; ++t) {
        const int pb = base + t * 16;
        if (t + 1 < TPW) issue(t + 1, xfn, hxmn, hx0n, hxpn, hsmn, hspn);

        const float gx = (hxm + 2.f * hx0 + hxp) * 0.125f;
        const float gy = (hsp - hsm) * 0.125f;

        bf16x8 a1;
        a1[0] = (__bf16)xf.x; a1[1] = (__bf16)xf.y;
        a1[2] = (__bf16)xf.z; a1[3] = (__bf16)xf.w;
        a1[4] = (__bf16)(g == 0 ? gx : (g == 1 ? 1.f : 0.f));
        a1[5] = (__bf16)(g == 0 ? gy : 0.f);
        a1[6] = (__bf16)0.f; a1[7] = (__bf16)0.f;

        f32x4 acc1[4];
#pragma unroll
        for (int n = 0; n < 4; ++n)
            acc1[n] = __builtin_amdgcn_mfma_f32_16x16x32_bf16(
                w1f[n], a1, (f32x4){0.f, 0.f, 0.f, 0.f}, 0, 0, 0);

        bf16x8 bf2[2];
#pragma unroll
        for (int s2 = 0; s2 < 2; ++s2)
#pragma unroll
            for (int j = 0; j < 4; ++j) {
                bf2[s2][j]     = (__bf16)fmaxf(acc1[2 * s2][j], 0.f);
                bf2[s2][4 + j] = (__bf16)fmaxf(acc1[2 * s2 + 1][j], 0.f);
            }

        f32x4 acc2[4];
#pragma unroll
        for (int n = 0; n < 4; ++n) {
            acc2[n] = b2v[n];
            acc2[n] = __builtin_amdgcn_mfma_f32_16x16x32_bf16(w2f[0][n], bf2[0], acc2[n], 0, 0, 0);
            acc2[n] = __builtin_amdgcn_mfma_f32_16x16x32_bf16(w2f[1][n], bf2[1], acc2[n], 0, 0, 0);
        }

        bf16x8 bf3[2];
#pragma unroll
        for (int s2 = 0; s2 < 2; ++s2)
#pragma unroll
            for (int j = 0; j < 4; ++j) {
                bf3[s2][j]     = (__bf16)fmaxf(acc2[2 * s2][j], 0.f);
                bf3[s2][4 + j] = (__bf16)fmaxf(acc2[2 * s2 + 1][j], 0.f);
            }

        f32x4 acc3 = __builtin_amdgcn_mfma_f32_16x16x32_bf16(
            w3f[0], bf3[0], (f32x4){0.f, 0.f, 0.f, 0.f}, 0, 0, 0);
        acc3 = __builtin_amdgcn_mfma_f32_16x16x32_bf16(w3f[1], bf3[1], acc3, 0, 0, 0);

        f32x4 xn;
        xn[0] = xf.x + acc3[0]; xn[1] = xf.y + acc3[1];
        xn[2] = xf.z + acc3[2]; xn[3] = xf.w + acc3[3];
        __builtin_nontemporal_store(xn, (f32x4*)(out + (size_t)(pb + r) * 16 + g * 4));
        if (g == 0) anewf[pb + r] = (xn[3] > THRV) ? 1 : 0;  // channel 3 post-flag

        if (t + 1 < TPW) {
            xf = xfn; hxm = hxmn; hx0 = hx0n; hxp = hxpn; hsm = hsmn; hsp = hspn;
        }
    }
}

// ---------------------------------------------------------------------------
// k_post: thread = 4 pixels. Bit-parallel life check on 0/1 byte flags:
// pre = vertical OR of rpref (already row-maxed); post = 3x3 OR of anewf.
// Zero dead pixels (rare) in place.
// ---------------------------------------------------------------------------
__global__ __launch_bounds__(256) void k_post(const unsigned char* __restrict__ rpref,
                                              const unsigned char* __restrict__ anewf,
                                              float* __restrict__ out) {
    const int q = blockIdx.x * 256 + threadIdx.x;
    const int p0 = q * 4;
    const int bi = p0 >> 16;
    const int rem = p0 & 65535;
    const int y = rem >> 8;
    const int c0 = rem & 255;
    const unsigned char* pr = rpref + ((size_t)bi << 16);
    const unsigned char* an = anewf + ((size_t)bi << 16);

    unsigned pre = 0, M = 0, l = 0, rr = 0;
#pragma unroll
    for (int dy = -1; dy <= 1; ++dy) {
        const int y2 = y + dy;
        if ((unsigned)y2 >= 256u) continue;
        const int ro = y2 * 256;
        pre |= *(const unsigned*)(pr + ro + c0);
        M   |= *(const unsigned*)(an + ro + c0);
        l   |= (c0 > 0)   ? (unsigned)an[ro + c0 - 1] : 0u;
        rr  |= (c0 < 252) ? (unsigned)an[ro + c0 + 4] : 0u;
    }
    const unsigned post = M | (M << 8) | l | (M >> 8) | (rr << 24);
    const unsigned alive = pre & post;
    if (alive != 0x01010101u) {
        const f32x4 z = (f32x4){0.f, 0.f, 0.f, 0.f};
#pragma unroll
        for (int i = 0; i < 4; ++i)
            if (!((alive >> (8 * i)) & 1u)) {
                f32x4* op = (f32x4*)(out + (size_t)(p0 + i) * 16);
                op[0] = z; op[1] = z; op[2] = z; op[3] = z;
            }
    }
}

// ---------------------------------------------------------------------------
extern "C" void kernel_launch(void* const* d_in, const int* in_sizes, int n_in,
                              void* d_out, int out_size, void* d_ws, size_t ws_size,
                              hipStream_t stream) {
    const float* x  = (const float*)d_in[0];
    const float* w1 = (const float*)d_in[1];
    const float* b1 = (const float*)d_in[2];
    const float* w2 = (const float*)d_in[3];
    const float* b2 = (const float*)d_in[4];
    const float* w3 = (const float*)d_in[5];
    float* out = (float*)d_out;

    float* hx = (float*)d_ws;                       // NPIX f32
    float* hs = hx + NPIX;                          // NPIX f32
    unsigned char* rpref = (unsigned char*)(hs + NPIX);  // NPIX bytes
    unsigned char* anewf = rpref + NPIX;                 // NPIX bytes
    float4* wpack = (float4*)(anewf + NPIX);             // NSLOT*64 float4

    hipLaunchKernelGGL(k_prep, dim3(NPIX / 256), dim3(256), 0, stream,
                       x, w1, b1, w2, b2, w3, hx, hs, rpref, wpack);
    hipLaunchKernelGGL(k_mfma, dim3(NPIX / 512), dim3(256), 0, stream,
                       x, hx, hs, wpack, out, anewf);
    hipLaunchKernelGGL(k_post, dim3(NPIX / 1024), dim3(256), 0, stream,
                       rpref, anewf, out);
}